// Round 1
// baseline (1125.887 us; speedup 1.0000x reference)
//
#include <hip/hip_runtime.h>
#include <math.h>

// ---------------- CSR build ----------------

__global__ __launch_bounds__(256) void k_count(const int* __restrict__ row,
                                               int* __restrict__ deg, int E) {
    int i = blockIdx.x * 256 + threadIdx.x;
    if (i < E) atomicAdd(&deg[row[i]], 1);
}

// wave-aggregated atomic allocation: start[i] = exclusive prefix of deg
__global__ __launch_bounds__(256) void k_alloc(const int* __restrict__ deg,
                                               int* __restrict__ start,
                                               int* __restrict__ cursor,
                                               int* counter, int N) {
    int i = blockIdx.x * 256 + threadIdx.x;
    int lane = threadIdx.x & 63;
    int d = (i < N) ? deg[i] : 0;
    int v = d;
#pragma unroll
    for (int off = 1; off < 64; off <<= 1) {
        int t = __shfl_up(v, off);
        if (lane >= off) v += t;
    }
    int total = __shfl(v, 63);
    int base = 0;
    if (lane == 63) base = atomicAdd(counter, total);
    base = __shfl(base, 63);
    if (i < N) {
        int s = base + v - d;
        start[i] = s;
        cursor[i] = s;
    }
}

__global__ __launch_bounds__(256) void k_fill(const int* __restrict__ row,
                                              const int* __restrict__ col,
                                              int* __restrict__ cursor,
                                              int* __restrict__ ccol, int E) {
    int i = blockIdx.x * 256 + threadIdx.x;
    if (i < E) {
        int p = atomicAdd(&cursor[row[i]], 1);
        ccol[p] = col[i];
    }
}

__global__ __launch_bounds__(256) void k_dinv(const int* __restrict__ deg,
                                              float* __restrict__ dinv, int N) {
    int i = blockIdx.x * 256 + threadIdx.x;
    if (i < N) {
        int d = deg[i];
        dinv[i] = (d > 0) ? 1.0f / sqrtf((float)d) : 0.0f;
    }
}

// ---------------- L_hat multiply (gather form) ----------------
// out[i][c] = a * (-dinv[i]) * sum_{j in adj(i)} dinv[j]*v[j][c]  + bc * other[i][c]
// one wave per row, lane = channel
template <int C>
__global__ __launch_bounds__(256) void k_lmul(const int* __restrict__ start,
                                              const int* __restrict__ deg,
                                              const int* __restrict__ ccol,
                                              const float* __restrict__ dinv,
                                              const float* __restrict__ v,
                                              const float* __restrict__ other,
                                              float* __restrict__ out, int N,
                                              float a, float bc) {
    int wid = threadIdx.x >> 6, lane = threadIdx.x & 63;
    int i = blockIdx.x * 4 + wid;
    if (i >= N) return;
    int s = start[i];
    int d = deg[i];
    float acc = 0.f;
    for (int k = 0; k < d; k++) {
        int j = ccol[s + k];
        float w = dinv[j];
        if (lane < C) acc += w * v[j * C + lane];
    }
    if (lane < C) {
        float r = a * (-dinv[i]) * acc;
        if (bc != 0.f) r += bc * other[i * C + lane];
        out[i * C + lane] = r;
    }
}

// ---------------- fused K=3 dense: out = [A0,A1,A2] @ Wcat + b (+ReLU) ----------------
// W layout: [3][C][COUT] contiguous. One wave per node; W staged in LDS.
template <int C, int COUT, bool RELU>
__global__ __launch_bounds__(256) void k_gemm(const float* __restrict__ A0,
                                              const float* __restrict__ A1,
                                              const float* __restrict__ A2,
                                              const float* __restrict__ W,
                                              const float* __restrict__ bias,
                                              float* __restrict__ out, int N) {
    __shared__ float Wl[3 * C * COUT + COUT];
    __shared__ float inl[4][3 * C];
    for (int t = threadIdx.x; t < 3 * C * COUT; t += 256) Wl[t] = W[t];
    for (int t = threadIdx.x; t < COUT; t += 256) Wl[3 * C * COUT + t] = bias[t];
    __syncthreads();
    int wid = threadIdx.x >> 6, lane = threadIdx.x & 63;
    int i0 = blockIdx.x * 4 + wid, stride = gridDim.x * 4;
    for (int i = i0; i < N; i += stride) {
        if (lane < C) {
            inl[wid][lane]         = A0[(size_t)i * C + lane];
            inl[wid][C + lane]     = A1[(size_t)i * C + lane];
            inl[wid][2 * C + lane] = A2[(size_t)i * C + lane];
        }
        // wave-internal LDS ordering (DS ops retire in order within a wave)
        if (lane < COUT) {
            float acc = Wl[3 * C * COUT + lane];
#pragma unroll 10
            for (int c = 0; c < 3 * C; c++) acc += inl[wid][c] * Wl[c * COUT + lane];
            if (RELU) acc = fmaxf(acc, 0.f);
            out[(size_t)i * COUT + lane] = acc;
        }
    }
}

extern "C" void kernel_launch(void* const* d_in, const int* in_sizes, int n_in,
                              void* d_out, int out_size, void* d_ws, size_t ws_size,
                              hipStream_t stream) {
    const float* x   = (const float*)d_in[0];
    const int*  eidx = (const int*)d_in[1];
    const float* W1  = (const float*)d_in[2];
    const float* b1  = (const float*)d_in[3];
    const float* W2  = (const float*)d_in[4];
    const float* b2  = (const float*)d_in[5];
    float* out = (float*)d_out;

    const int CIN = 50, CH = 50, COUT = 40;
    int N = in_sizes[0] / CIN;  // 100000
    int E = in_sizes[1] / 2;    // 1600000
    const int* row = eidx;
    const int* col = eidx + E;

    // workspace carve-up
    char* w = (char*)d_ws;
    auto carve = [&](size_t b) -> char* {
        char* p = w;
        w += (b + 255) & ~(size_t)255;
        return p;
    };
    int*   deg     = (int*)carve((size_t)N * 4);
    int*   start   = (int*)carve((size_t)N * 4);
    int*   cursor  = (int*)carve((size_t)N * 4);
    int*   counter = (int*)carve(256);
    float* dinv    = (float*)carve((size_t)N * 4);
    int*   ccol    = (int*)carve((size_t)E * 4);
    float* B1      = (float*)carve((size_t)N * CH * 4);
    float* B2      = (float*)carve((size_t)N * CH * 4);
    float* H       = (float*)carve((size_t)N * CH * 4);
    (void)ws_size; (void)n_in; (void)out_size;

    hipMemsetAsync(deg, 0, (size_t)N * 4, stream);
    hipMemsetAsync(counter, 0, 4, stream);

    int gE = (E + 255) / 256;
    int gN = (N + 255) / 256;
    int gW = (N + 3) / 4;

    k_count<<<gE, 256, 0, stream>>>(row, deg, E);
    k_alloc<<<gN, 256, 0, stream>>>(deg, start, cursor, counter, N);
    k_fill<<<gE, 256, 0, stream>>>(row, col, cursor, ccol, E);
    k_dinv<<<gN, 256, 0, stream>>>(deg, dinv, N);

    // layer 1: Tx1 = L x ; Tx2 = 2 L Tx1 - x ; H = relu([x,Tx1,Tx2]@W1 + b1)
    k_lmul<50><<<gW, 256, 0, stream>>>(start, deg, ccol, dinv, x, x, B1, N, 1.f, 0.f);
    k_lmul<50><<<gW, 256, 0, stream>>>(start, deg, ccol, dinv, B1, x, B2, N, 2.f, -1.f);
    k_gemm<50, 50, true><<<2048, 256, 0, stream>>>(x, B1, B2, W1, b1, H, N);

    // layer 2: Tx1 = L H ; Tx2 = 2 L Tx1 - H ; out = [H,Tx1,Tx2]@W2 + b2
    k_lmul<50><<<gW, 256, 0, stream>>>(start, deg, ccol, dinv, H, H, B1, N, 1.f, 0.f);
    k_lmul<50><<<gW, 256, 0, stream>>>(start, deg, ccol, dinv, B1, H, B2, N, 2.f, -1.f);
    k_gemm<50, 40, false><<<2048, 256, 0, stream>>>(H, B1, B2, W2, b2, out, N);
}

// Round 2
// 1091.612 us; speedup vs baseline: 1.0314x; 1.0314x over previous
//
#include <hip/hip_runtime.h>
#include <math.h>

// ---------------- CSR build ----------------

__global__ __launch_bounds__(256) void k_count(const int* __restrict__ row,
                                               int* __restrict__ deg, int E) {
    int i = blockIdx.x * 256 + threadIdx.x;
    if (i < E) atomicAdd(&deg[row[i]], 1);
}

// wave-aggregated atomic allocation: start[i] = exclusive prefix of deg
__global__ __launch_bounds__(256) void k_alloc(const int* __restrict__ deg,
                                               int* __restrict__ start,
                                               int* __restrict__ cursor,
                                               int* counter, int N) {
    int i = blockIdx.x * 256 + threadIdx.x;
    int lane = threadIdx.x & 63;
    int d = (i < N) ? deg[i] : 0;
    int v = d;
#pragma unroll
    for (int off = 1; off < 64; off <<= 1) {
        int t = __shfl_up(v, off);
        if (lane >= off) v += t;
    }
    int total = __shfl(v, 63);
    int base = 0;
    if (lane == 63) base = atomicAdd(counter, total);
    base = __shfl(base, 63);
    if (i < N) {
        int s = base + v - d;
        start[i] = s;
        cursor[i] = s;
    }
}

__global__ __launch_bounds__(256) void k_fill(const int* __restrict__ row,
                                              const int* __restrict__ col,
                                              int* __restrict__ cursor,
                                              int* __restrict__ ccol, int E) {
    int i = blockIdx.x * 256 + threadIdx.x;
    if (i < E) {
        int p = atomicAdd(&cursor[row[i]], 1);
        ccol[p] = col[i];
    }
}

__global__ __launch_bounds__(256) void k_dinv(const int* __restrict__ deg,
                                              float* __restrict__ dinv, int N) {
    int i = blockIdx.x * 256 + threadIdx.x;
    if (i < N) {
        int d = deg[i];
        dinv[i] = (d > 0) ? 1.0f / sqrtf((float)d) : 0.0f;
    }
}

// per-edge weight cd[e] = dinv[ccol[e]] (one-time gather, removes a dependent
// load from every lmul edge visit)
__global__ __launch_bounds__(256) void k_edgew(const int* __restrict__ ccol,
                                               const float* __restrict__ dinv,
                                               float* __restrict__ cd, int E) {
    int i = blockIdx.x * 256 + threadIdx.x;
    if (i < E) cd[i] = dinv[ccol[i]];
}

// ---------------- L_hat multiply (gather form, unroll-8 for MLP) ----------------
// out[i][c] = -a * dinv[i] * sum_e cd[e]*v[ccol[e]][c]  + bc * other[i][c]
template <int C>
__global__ __launch_bounds__(256) void k_lmul(const int* __restrict__ start,
                                              const int* __restrict__ deg,
                                              const int* __restrict__ ccol,
                                              const float* __restrict__ cd,
                                              const float* __restrict__ dinv,
                                              const float* __restrict__ v,
                                              const float* __restrict__ other,
                                              float* __restrict__ out, int N,
                                              float a, float bc) {
    int wid = threadIdx.x >> 6, lane = threadIdx.x & 63;
    int i = blockIdx.x * 4 + wid;
    if (i >= N || lane >= C) return;
    int s = start[i];
    int d = deg[i];
    float acc = 0.f;
    int k = 0;
    for (; k + 8 <= d; k += 8) {
        // 16 independent stream loads (ccol, cd), then 8 independent gathers
        int j0 = ccol[s + k + 0], j1 = ccol[s + k + 1];
        int j2 = ccol[s + k + 2], j3 = ccol[s + k + 3];
        int j4 = ccol[s + k + 4], j5 = ccol[s + k + 5];
        int j6 = ccol[s + k + 6], j7 = ccol[s + k + 7];
        float w0 = cd[s + k + 0], w1 = cd[s + k + 1];
        float w2 = cd[s + k + 2], w3 = cd[s + k + 3];
        float w4 = cd[s + k + 4], w5 = cd[s + k + 5];
        float w6 = cd[s + k + 6], w7 = cd[s + k + 7];
        float t0 = w0 * v[(size_t)j0 * C + lane];
        float t1 = w1 * v[(size_t)j1 * C + lane];
        float t2 = w2 * v[(size_t)j2 * C + lane];
        float t3 = w3 * v[(size_t)j3 * C + lane];
        float t4 = w4 * v[(size_t)j4 * C + lane];
        float t5 = w5 * v[(size_t)j5 * C + lane];
        float t6 = w6 * v[(size_t)j6 * C + lane];
        float t7 = w7 * v[(size_t)j7 * C + lane];
        acc += ((t0 + t1) + (t2 + t3)) + ((t4 + t5) + (t6 + t7));
    }
    for (; k < d; ++k)
        acc += cd[s + k] * v[(size_t)ccol[s + k] * C + lane];
    float r = -a * dinv[i] * acc;
    if (bc != 0.f) r += bc * other[(size_t)i * C + lane];
    out[(size_t)i * C + lane] = r;
}

// ---------------- register GEMM: out = [A0,A1,A2] @ Wcat + b (+ReLU) ----------------
// lane = cout (COUT<=64 active). W chunk of 50 rows held in VGPRs (one chunk per
// A-array). A elements are wave-uniform loads (1 cache line each, L1/L2-hot).
// Zero LDS. 8 rows per wave per pass; N must be a multiple of 8.
template <int COUT, bool RELU>
__global__ __launch_bounds__(256) void k_gemm(const float* __restrict__ A0,
                                              const float* __restrict__ A1,
                                              const float* __restrict__ A2,
                                              const float* __restrict__ W,
                                              const float* __restrict__ bias,
                                              float* __restrict__ out, int N) {
    int lane = threadIdx.x & 63;
    int wave = blockIdx.x * 4 + (threadIdx.x >> 6);
    int nw = gridDim.x * 4;
    bool act = lane < COUT;
    float bs = act ? bias[lane] : 0.f;
    for (int base = wave * 8; base + 8 <= N; base += nw * 8) {
        float acc[8];
#pragma unroll
        for (int r = 0; r < 8; ++r) acc[r] = bs;
        const float* Aarr[3] = {A0, A1, A2};
#pragma unroll
        for (int arr = 0; arr < 3; ++arr) {
            float wreg[50];
#pragma unroll
            for (int c = 0; c < 50; ++c)
                wreg[c] = act ? W[(size_t)(arr * 50 + c) * COUT + lane] : 0.f;
            const float* Aa = Aarr[arr] + (size_t)base * 50;
#pragma unroll
            for (int r = 0; r < 8; ++r) {
#pragma unroll
                for (int h = 0; h < 25; ++h) {
                    float2 av = *(const float2*)(Aa + r * 50 + h * 2);
                    acc[r] += av.x * wreg[2 * h] + av.y * wreg[2 * h + 1];
                }
            }
        }
#pragma unroll
        for (int r = 0; r < 8; ++r) {
            float vv = acc[r];
            if (RELU) vv = fmaxf(vv, 0.f);
            if (act) out[(size_t)(base + r) * COUT + lane] = vv;
        }
    }
}

extern "C" void kernel_launch(void* const* d_in, const int* in_sizes, int n_in,
                              void* d_out, int out_size, void* d_ws, size_t ws_size,
                              hipStream_t stream) {
    const float* x   = (const float*)d_in[0];
    const int*  eidx = (const int*)d_in[1];
    const float* W1  = (const float*)d_in[2];
    const float* b1  = (const float*)d_in[3];
    const float* W2  = (const float*)d_in[4];
    const float* b2  = (const float*)d_in[5];
    float* out = (float*)d_out;

    const int CIN = 50, CH = 50, COUT = 40;
    int N = in_sizes[0] / CIN;  // 100000
    int E = in_sizes[1] / 2;    // 1600000
    const int* row = eidx;
    const int* col = eidx + E;

    // workspace carve-up
    char* w = (char*)d_ws;
    auto carve = [&](size_t b) -> char* {
        char* p = w;
        w += (b + 255) & ~(size_t)255;
        return p;
    };
    int*   deg     = (int*)carve((size_t)N * 4);
    int*   start   = (int*)carve((size_t)N * 4);
    int*   cursor  = (int*)carve((size_t)N * 4);
    int*   counter = (int*)carve(256);
    float* dinv    = (float*)carve((size_t)N * 4);
    int*   ccol    = (int*)carve((size_t)E * 4);
    float* cd      = (float*)carve((size_t)E * 4);
    // +256B pad: lmul gathers read v[j*50 + lane] for lane up to 63
    float* B1      = (float*)carve((size_t)N * CH * 4 + 256);
    float* B2      = (float*)carve((size_t)N * CH * 4 + 256);
    float* H       = (float*)carve((size_t)N * CH * 4 + 256);
    (void)ws_size; (void)n_in; (void)out_size;

    hipMemsetAsync(deg, 0, (size_t)N * 4, stream);
    hipMemsetAsync(counter, 0, 4, stream);

    int gE = (E + 255) / 256;
    int gN = (N + 255) / 256;
    int gW = (N + 3) / 4;

    k_count<<<gE, 256, 0, stream>>>(row, deg, E);
    k_alloc<<<gN, 256, 0, stream>>>(deg, start, cursor, counter, N);
    k_fill<<<gE, 256, 0, stream>>>(row, col, cursor, ccol, E);
    k_dinv<<<gN, 256, 0, stream>>>(deg, dinv, N);
    k_edgew<<<gE, 256, 0, stream>>>(ccol, dinv, cd, E);

    int gG = 3125;  // N/8/4 waves -> one 8-row pass per wave

    // layer 1: Tx1 = L x ; Tx2 = 2 L Tx1 - x ; H = relu([x,Tx1,Tx2]@W1 + b1)
    k_lmul<50><<<gW, 256, 0, stream>>>(start, deg, ccol, cd, dinv, x, x, B1, N, 1.f, 0.f);
    k_lmul<50><<<gW, 256, 0, stream>>>(start, deg, ccol, cd, dinv, B1, x, B2, N, 2.f, -1.f);
    k_gemm<50, true><<<gG, 256, 0, stream>>>(x, B1, B2, W1, b1, H, N);

    // layer 2: Tx1 = L H ; Tx2 = 2 L Tx1 - H ; out = [H,Tx1,Tx2]@W2 + b2
    k_lmul<50><<<gW, 256, 0, stream>>>(start, deg, ccol, cd, dinv, H, H, B1, N, 1.f, 0.f);
    k_lmul<50><<<gW, 256, 0, stream>>>(start, deg, ccol, cd, dinv, B1, H, B2, N, 2.f, -1.f);
    k_gemm<40, false><<<gG, 256, 0, stream>>>(H, B1, B2, W2, b2, out, N);
}

// Round 3
// 542.867 us; speedup vs baseline: 2.0740x; 2.0108x over previous
//
#include <hip/hip_runtime.h>
#include <hip/hip_bf16.h>
#include <math.h>

typedef short bf16x8 __attribute__((ext_vector_type(8)));
typedef float f32x4 __attribute__((ext_vector_type(4)));
typedef __hip_bfloat16 bf16;

static __device__ __forceinline__ float bf2f(ushort u) {
    unsigned int x = ((unsigned int)u) << 16;
    return __builtin_bit_cast(float, x);
}
static __device__ __forceinline__ ushort f2bf(float f) {
    bf16 h = __float2bfloat16(f);
    return __builtin_bit_cast(ushort, h);
}

// ---------------- CSR build ----------------

__global__ __launch_bounds__(256) void k_count(const int* __restrict__ row,
                                               int* __restrict__ deg, int E) {
    int i = blockIdx.x * 256 + threadIdx.x;
    if (i < E) atomicAdd(&deg[row[i]], 1);
}

__global__ __launch_bounds__(256) void k_alloc(const int* __restrict__ deg,
                                               int* __restrict__ start,
                                               int* __restrict__ cursor,
                                               int* counter, int N) {
    int i = blockIdx.x * 256 + threadIdx.x;
    int lane = threadIdx.x & 63;
    int d = (i < N) ? deg[i] : 0;
    int v = d;
#pragma unroll
    for (int off = 1; off < 64; off <<= 1) {
        int t = __shfl_up(v, off);
        if (lane >= off) v += t;
    }
    int total = __shfl(v, 63);
    int base = 0;
    if (lane == 63) base = atomicAdd(counter, total);
    base = __shfl(base, 63);
    if (i < N) {
        int s = base + v - d;
        start[i] = s;
        cursor[i] = s;
    }
}

__global__ __launch_bounds__(256) void k_dinv(const int* __restrict__ deg,
                                              float* __restrict__ dinv, int N) {
    int i = blockIdx.x * 256 + threadIdx.x;
    if (i < N) {
        int d = deg[i];
        dinv[i] = (d > 0) ? 1.0f / sqrtf((float)d) : 0.0f;
    }
}

// fill CSR columns AND per-edge weight cd[p] = dinv[col]
__global__ __launch_bounds__(256) void k_fill(const int* __restrict__ row,
                                              const int* __restrict__ col,
                                              int* __restrict__ cursor,
                                              const float* __restrict__ dinv,
                                              int* __restrict__ ccol,
                                              float* __restrict__ cd, int E) {
    int i = blockIdx.x * 256 + threadIdx.x;
    if (i < E) {
        int c = col[i];
        int p = atomicAdd(&cursor[row[i]], 1);
        ccol[p] = c;
        cd[p] = dinv[c];
    }
}

// ---------------- layout prep ----------------
// x f32 [N][50] -> xb bf16 [N][64] (zero-padded channels)
__global__ __launch_bounds__(256) void k_pad_x(const float* __restrict__ x,
                                               ushort* __restrict__ xb, int N) {
    int t = blockIdx.x * 256 + threadIdx.x;
    if (t >= N * 64) return;
    int i = t >> 6, c = t & 63;
    float v = (c < 50) ? x[(size_t)i * 50 + c] : 0.f;
    xb[t] = f2bf(v);
}

// W f32 [3][50][COUT] -> Wt bf16 [64][192] (Wt[cout][arr*64+c]), zero-padded
template <int COUT>
__global__ __launch_bounds__(256) void k_wt(const float* __restrict__ W,
                                            ushort* __restrict__ Wt) {
    int t = blockIdx.x * 256 + threadIdx.x;
    if (t >= 64 * 192) return;
    int cout = t / 192, k = t % 192;
    int arr = k >> 6, c = k & 63;
    float v = (c < 50 && cout < COUT) ? W[(size_t)(arr * 50 + c) * COUT + cout] : 0.f;
    Wt[t] = f2bf(v);
}

// ---------------- L_hat multiply (bf16 padded-64 rows: 1 line/edge) ----------------
// out[i][c] = -a*dinv[i] * sum_e cd[e]*v[ccol[e]][c]  + bc*other[i][c]
__global__ __launch_bounds__(256) void k_lmul(const int* __restrict__ start,
                                              const int* __restrict__ deg,
                                              const int* __restrict__ ccol,
                                              const float* __restrict__ cd,
                                              const float* __restrict__ dinv,
                                              const ushort* __restrict__ v,
                                              const ushort* __restrict__ other,
                                              ushort* __restrict__ out, int N,
                                              float a, float bc) {
    int wid = threadIdx.x >> 6, lane = threadIdx.x & 63;
    int i = blockIdx.x * 4 + wid;
    if (i >= N) return;
    int s = start[i];
    int d = deg[i];
    float acc = 0.f;
    int k = 0;
    for (; k + 8 <= d; k += 8) {
        int j0 = ccol[s + k + 0], j1 = ccol[s + k + 1];
        int j2 = ccol[s + k + 2], j3 = ccol[s + k + 3];
        int j4 = ccol[s + k + 4], j5 = ccol[s + k + 5];
        int j6 = ccol[s + k + 6], j7 = ccol[s + k + 7];
        float w0 = cd[s + k + 0], w1 = cd[s + k + 1];
        float w2 = cd[s + k + 2], w3 = cd[s + k + 3];
        float w4 = cd[s + k + 4], w5 = cd[s + k + 5];
        float w6 = cd[s + k + 6], w7 = cd[s + k + 7];
        float t0 = w0 * bf2f(v[(size_t)j0 * 64 + lane]);
        float t1 = w1 * bf2f(v[(size_t)j1 * 64 + lane]);
        float t2 = w2 * bf2f(v[(size_t)j2 * 64 + lane]);
        float t3 = w3 * bf2f(v[(size_t)j3 * 64 + lane]);
        float t4 = w4 * bf2f(v[(size_t)j4 * 64 + lane]);
        float t5 = w5 * bf2f(v[(size_t)j5 * 64 + lane]);
        float t6 = w6 * bf2f(v[(size_t)j6 * 64 + lane]);
        float t7 = w7 * bf2f(v[(size_t)j7 * 64 + lane]);
        acc += ((t0 + t1) + (t2 + t3)) + ((t4 + t5) + (t6 + t7));
    }
    for (; k < d; ++k)
        acc += cd[s + k] * bf2f(v[(size_t)ccol[s + k] * 64 + lane]);
    float r = -a * dinv[i] * acc;
    if (bc != 0.f) r += bc * bf2f(other[(size_t)i * 64 + lane]);
    out[(size_t)i * 64 + lane] = f2bf(r);
}

// ---------------- MFMA GEMM: C[N, NCT*16] = [A0|A1|A2] @ Wt^T + b ----------------
// A*: bf16 [N][64] padded; Wt: bf16 [64][192]. One 16x16 tile per wave per step.
// BF16OUT: store bf16 padded-64 (H); else f32 [N][40] masked col<40.
template <int NCT, bool RELU, bool BF16OUT>
__global__ __launch_bounds__(256) void k_gemm_mfma(const ushort* __restrict__ A0,
                                                   const ushort* __restrict__ A1,
                                                   const ushort* __restrict__ A2,
                                                   const ushort* __restrict__ Wt,
                                                   const float* __restrict__ bias,
                                                   int biasN,
                                                   ushort* __restrict__ outb,
                                                   float* __restrict__ outf, int N) {
    int lane = threadIdx.x & 63;
    int wv = blockIdx.x * 4 + (threadIdx.x >> 6);
    int nw = gridDim.x * 4;
    int r15 = lane & 15, kq = lane >> 4;  // kq in 0..3

    // preload B fragments: b[s][ct], s = K-step (k=s*32..s*32+31), ct = cout tile
    bf16x8 bfr[6][NCT];
#pragma unroll
    for (int s = 0; s < 6; ++s)
#pragma unroll
        for (int ct = 0; ct < NCT; ++ct)
            bfr[s][ct] = *(const bf16x8*)(Wt + (size_t)(ct * 16 + r15) * 192 + s * 32 + kq * 8);
    float bs[NCT];
#pragma unroll
    for (int ct = 0; ct < NCT; ++ct) {
        int col = ct * 16 + r15;
        bs[ct] = (col < biasN) ? bias[col] : 0.f;
    }

    const ushort* As[3] = {A0, A1, A2};
    int ntile = N >> 4;
    for (int t = wv; t < ntile; t += nw) {
        int rb = t << 4;
        bf16x8 af[6];
#pragma unroll
        for (int s = 0; s < 6; ++s)
            af[s] = *(const bf16x8*)(As[s >> 1] + (size_t)(rb + r15) * 64 + (s & 1) * 32 + kq * 8);
        f32x4 acc[NCT];
#pragma unroll
        for (int ct = 0; ct < NCT; ++ct) acc[ct] = (f32x4){0.f, 0.f, 0.f, 0.f};
#pragma unroll
        for (int s = 0; s < 6; ++s)
#pragma unroll
            for (int ct = 0; ct < NCT; ++ct)
                acc[ct] = __builtin_amdgcn_mfma_f32_16x16x32_bf16(af[s], bfr[s][ct], acc[ct], 0, 0, 0);
#pragma unroll
        for (int ct = 0; ct < NCT; ++ct) {
            int col = ct * 16 + r15;
#pragma unroll
            for (int i = 0; i < 4; ++i) {
                int row = rb + kq * 4 + i;  // C/D: col=lane&15, row=(lane>>4)*4+i  [m89]
                float v = acc[ct][i] + bs[ct];
                if (RELU) v = fmaxf(v, 0.f);
                if (BF16OUT) {
                    outb[(size_t)row * 64 + col] = f2bf(v);
                } else {
                    if (col < 40) outf[(size_t)row * 40 + col] = v;
                }
            }
        }
    }
}

extern "C" void kernel_launch(void* const* d_in, const int* in_sizes, int n_in,
                              void* d_out, int out_size, void* d_ws, size_t ws_size,
                              hipStream_t stream) {
    const float* x   = (const float*)d_in[0];
    const int*  eidx = (const int*)d_in[1];
    const float* W1  = (const float*)d_in[2];
    const float* b1  = (const float*)d_in[3];
    const float* W2  = (const float*)d_in[4];
    const float* b2  = (const float*)d_in[5];
    float* out = (float*)d_out;

    const int CIN = 50;
    int N = in_sizes[0] / CIN;  // 100000
    int E = in_sizes[1] / 2;    // 1600000
    const int* row = eidx;
    const int* col = eidx + E;

    char* w = (char*)d_ws;
    auto carve = [&](size_t b) -> char* {
        char* p = w;
        w += (b + 255) & ~(size_t)255;
        return p;
    };
    int*    deg     = (int*)carve((size_t)N * 4);
    int*    start   = (int*)carve((size_t)N * 4);
    int*    cursor  = (int*)carve((size_t)N * 4);
    int*    counter = (int*)carve(256);
    float*  dinv    = (float*)carve((size_t)N * 4);
    int*    ccol    = (int*)carve((size_t)E * 4);
    float*  cd      = (float*)carve((size_t)E * 4);
    ushort* xb      = (ushort*)carve((size_t)N * 64 * 2);
    ushort* B1b     = (ushort*)carve((size_t)N * 64 * 2);
    ushort* B2b     = (ushort*)carve((size_t)N * 64 * 2);
    ushort* Hb      = (ushort*)carve((size_t)N * 64 * 2);
    ushort* Wt1     = (ushort*)carve((size_t)64 * 192 * 2);
    ushort* Wt2     = (ushort*)carve((size_t)64 * 192 * 2);
    (void)ws_size; (void)n_in; (void)out_size;

    hipMemsetAsync(deg, 0, (size_t)N * 4, stream);
    hipMemsetAsync(counter, 0, 4, stream);

    int gE = (E + 255) / 256;
    int gN = (N + 255) / 256;
    int gW = (N + 3) / 4;

    k_count<<<gE, 256, 0, stream>>>(row, deg, E);
    k_alloc<<<gN, 256, 0, stream>>>(deg, start, cursor, counter, N);
    k_dinv<<<gN, 256, 0, stream>>>(deg, dinv, N);
    k_fill<<<gE, 256, 0, stream>>>(row, col, cursor, dinv, ccol, cd, E);
    k_pad_x<<<(N * 64 + 255) / 256, 256, 0, stream>>>(x, xb, N);
    k_wt<50><<<(64 * 192 + 255) / 256, 256, 0, stream>>>(W1, Wt1);
    k_wt<40><<<(64 * 192 + 255) / 256, 256, 0, stream>>>(W2, Wt2);

    int gG = 392;  // 1568 waves, ~4 row-tiles each

    // layer 1
    k_lmul<<<gW, 256, 0, stream>>>(start, deg, ccol, cd, dinv, xb, xb, B1b, N, 1.f, 0.f);
    k_lmul<<<gW, 256, 0, stream>>>(start, deg, ccol, cd, dinv, B1b, xb, B2b, N, 2.f, -1.f);
    k_gemm_mfma<4, true, true><<<gG, 256, 0, stream>>>(xb, B1b, B2b, Wt1, b1, 50, Hb, nullptr, N);

    // layer 2
    k_lmul<<<gW, 256, 0, stream>>>(start, deg, ccol, cd, dinv, Hb, Hb, B1b, N, 1.f, 0.f);
    k_lmul<<<gW, 256, 0, stream>>>(start, deg, ccol, cd, dinv, B1b, Hb, B2b, N, 2.f, -1.f);
    k_gemm_mfma<3, false, false><<<gG, 256, 0, stream>>>(Hb, B1b, B2b, Wt2, b2, 40, nullptr, out, N);
}

// Round 4
// 519.479 us; speedup vs baseline: 2.1673x; 1.0450x over previous
//
#include <hip/hip_runtime.h>
#include <hip/hip_bf16.h>
#include <math.h>

typedef short bf16x8 __attribute__((ext_vector_type(8)));
typedef float f32x4 __attribute__((ext_vector_type(4)));
typedef __hip_bfloat16 bf16;

static __device__ __forceinline__ float bf2f(ushort u) {
    unsigned int x = ((unsigned int)u) << 16;
    return __builtin_bit_cast(float, x);
}
static __device__ __forceinline__ ushort f2bf(float f) {
    bf16 h = __float2bfloat16(f);
    return __builtin_bit_cast(ushort, h);
}

// ---------------- CSR build ----------------

__global__ __launch_bounds__(256) void k_count(const int* __restrict__ row,
                                               int* __restrict__ deg, int E) {
    int i = blockIdx.x * 256 + threadIdx.x;
    if (i < E) atomicAdd(&deg[row[i]], 1);
}

// start = exclusive prefix of deg (wave-aggregated atomic alloc); also dinv
__global__ __launch_bounds__(256) void k_alloc(const int* __restrict__ deg,
                                               int* __restrict__ start,
                                               int* __restrict__ cursor,
                                               float* __restrict__ dinv,
                                               int* counter, int N) {
    int i = blockIdx.x * 256 + threadIdx.x;
    int lane = threadIdx.x & 63;
    int d = (i < N) ? deg[i] : 0;
    int v = d;
#pragma unroll
    for (int off = 1; off < 64; off <<= 1) {
        int t = __shfl_up(v, off);
        if (lane >= off) v += t;
    }
    int total = __shfl(v, 63);
    int base = 0;
    if (lane == 63) base = atomicAdd(counter, total);
    base = __shfl(base, 63);
    if (i < N) {
        int s = base + v - d;
        start[i] = s;
        cursor[i] = s;
        dinv[i] = (d > 0) ? 1.0f / sqrtf((float)d) : 0.0f;
    }
}

// windowed fill: only edges whose row is in [lo,hi) are placed this pass, so the
// scattered int2 writes stay within a ~3.2MB region that fits a per-XCD L2.
__global__ __launch_bounds__(256) void k_fill(const int* __restrict__ row,
                                              const int* __restrict__ col,
                                              int* __restrict__ cursor,
                                              const float* __restrict__ dinv,
                                              int2* __restrict__ ecc, int E,
                                              int lo, int hi) {
    int i = blockIdx.x * 256 + threadIdx.x;
    if (i >= E) return;
    int r = row[i];
    if (r < lo || r >= hi) return;
    int c = col[i];
    int p = atomicAdd(&cursor[r], 1);
    int2 pk;
    pk.x = c;
    pk.y = __float_as_int(dinv[c]);
    ecc[p] = pk;
}

// ---------------- layout prep ----------------
__global__ __launch_bounds__(256) void k_pad_x(const float* __restrict__ x,
                                               ushort* __restrict__ xb, int N) {
    int t = blockIdx.x * 256 + threadIdx.x;
    if (t >= N * 64) return;
    int i = t >> 6, c = t & 63;
    float v = (c < 50) ? x[(size_t)i * 50 + c] : 0.f;
    xb[t] = f2bf(v);
}

// both weight transposes in one launch: Wt[cout][arr*64+c], bf16, zero-padded
__global__ __launch_bounds__(256) void k_wt(const float* __restrict__ W1,
                                            const float* __restrict__ W2,
                                            ushort* __restrict__ Wt1,
                                            ushort* __restrict__ Wt2) {
    int t = blockIdx.x * 256 + threadIdx.x;
    if (t >= 2 * 64 * 192) return;
    int half = t / (64 * 192), u = t % (64 * 192);
    int cout = u / 192, k = u % 192;
    int arr = k >> 6, c = k & 63;
    if (half == 0) {
        float v = (c < 50) ? W1[(size_t)(arr * 50 + c) * 50 + cout] : 0.f;
        Wt1[u] = f2bf(v);
    } else {
        float v = (c < 50 && cout < 40) ? W2[(size_t)(arr * 50 + c) * 40 + cout] : 0.f;
        Wt2[u] = f2bf(v);
    }
}

// ---------------- L_hat multiply ----------------
// out[i][c] = -a*dinv[i]*sum_e w_e * v[col_e][c] + bc*other[i][c]
// bf16 rows padded to 64 ch = 128B = 1 line per gather. Pipelined headers:
// next 8 edge headers issue while current 8 gathers are in flight.
__global__ __launch_bounds__(256) void k_lmul(const int* __restrict__ start,
                                              const int* __restrict__ deg,
                                              const int2* __restrict__ ecc,
                                              const float* __restrict__ dinv,
                                              const ushort* __restrict__ v,
                                              const ushort* __restrict__ other,
                                              ushort* __restrict__ out, int N,
                                              float a, float bc) {
    int wid = threadIdx.x >> 6, lane = threadIdx.x & 63;
    int i = blockIdx.x * 4 + wid;
    if (i >= N) return;
    int s = start[i];
    int d = deg[i];
    float acc = 0.f;
    int k = 0;
    if (d >= 8) {
        int2 e0 = ecc[s + 0], e1 = ecc[s + 1], e2 = ecc[s + 2], e3 = ecc[s + 3];
        int2 e4 = ecc[s + 4], e5 = ecc[s + 5], e6 = ecc[s + 6], e7 = ecc[s + 7];
        for (; k + 16 <= d; k += 8) {
            int b = s + k + 8;
            int2 n0 = ecc[b + 0], n1 = ecc[b + 1], n2 = ecc[b + 2], n3 = ecc[b + 3];
            int2 n4 = ecc[b + 4], n5 = ecc[b + 5], n6 = ecc[b + 6], n7 = ecc[b + 7];
            float t0 = __int_as_float(e0.y) * bf2f(v[(size_t)e0.x * 64 + lane]);
            float t1 = __int_as_float(e1.y) * bf2f(v[(size_t)e1.x * 64 + lane]);
            float t2 = __int_as_float(e2.y) * bf2f(v[(size_t)e2.x * 64 + lane]);
            float t3 = __int_as_float(e3.y) * bf2f(v[(size_t)e3.x * 64 + lane]);
            float t4 = __int_as_float(e4.y) * bf2f(v[(size_t)e4.x * 64 + lane]);
            float t5 = __int_as_float(e5.y) * bf2f(v[(size_t)e5.x * 64 + lane]);
            float t6 = __int_as_float(e6.y) * bf2f(v[(size_t)e6.x * 64 + lane]);
            float t7 = __int_as_float(e7.y) * bf2f(v[(size_t)e7.x * 64 + lane]);
            acc += ((t0 + t1) + (t2 + t3)) + ((t4 + t5) + (t6 + t7));
            e0 = n0; e1 = n1; e2 = n2; e3 = n3;
            e4 = n4; e5 = n5; e6 = n6; e7 = n7;
        }
        {   // drain the preloaded block [k, k+8)
            float t0 = __int_as_float(e0.y) * bf2f(v[(size_t)e0.x * 64 + lane]);
            float t1 = __int_as_float(e1.y) * bf2f(v[(size_t)e1.x * 64 + lane]);
            float t2 = __int_as_float(e2.y) * bf2f(v[(size_t)e2.x * 64 + lane]);
            float t3 = __int_as_float(e3.y) * bf2f(v[(size_t)e3.x * 64 + lane]);
            float t4 = __int_as_float(e4.y) * bf2f(v[(size_t)e4.x * 64 + lane]);
            float t5 = __int_as_float(e5.y) * bf2f(v[(size_t)e5.x * 64 + lane]);
            float t6 = __int_as_float(e6.y) * bf2f(v[(size_t)e6.x * 64 + lane]);
            float t7 = __int_as_float(e7.y) * bf2f(v[(size_t)e7.x * 64 + lane]);
            acc += ((t0 + t1) + (t2 + t3)) + ((t4 + t5) + (t6 + t7));
            k += 8;
        }
    }
    for (; k < d; ++k) {
        int2 e = ecc[s + k];
        acc += __int_as_float(e.y) * bf2f(v[(size_t)e.x * 64 + lane]);
    }
    float r = -a * dinv[i] * acc;
    if (bc != 0.f) r += bc * bf2f(other[(size_t)i * 64 + lane]);
    out[(size_t)i * 64 + lane] = f2bf(r);
}

// ---------------- MFMA GEMM: C[N, NCT*16] = [A0|A1|A2] @ Wt^T + b ----------------
// depth-2 pipeline on the A fragments (next tile's loads issue before MFMAs).
template <int NCT, bool RELU, bool BF16OUT>
__global__ __launch_bounds__(256) void k_gemm_mfma(const ushort* __restrict__ A0,
                                                   const ushort* __restrict__ A1,
                                                   const ushort* __restrict__ A2,
                                                   const ushort* __restrict__ Wt,
                                                   const float* __restrict__ bias,
                                                   int biasN,
                                                   ushort* __restrict__ outb,
                                                   float* __restrict__ outf, int N) {
    int lane = threadIdx.x & 63;
    int wv = blockIdx.x * 4 + (threadIdx.x >> 6);
    int nw = gridDim.x * 4;
    int r15 = lane & 15, kq = lane >> 4;

    bf16x8 bfr[6][NCT];
#pragma unroll
    for (int s = 0; s < 6; ++s)
#pragma unroll
        for (int ct = 0; ct < NCT; ++ct)
            bfr[s][ct] = *(const bf16x8*)(Wt + (size_t)(ct * 16 + r15) * 192 + s * 32 + kq * 8);
    float bs[NCT];
#pragma unroll
    for (int ct = 0; ct < NCT; ++ct) {
        int col = ct * 16 + r15;
        bs[ct] = (col < biasN) ? bias[col] : 0.f;
    }

    const ushort* As[3] = {A0, A1, A2};
    int ntile = N >> 4;
    if (wv >= ntile) return;
    bf16x8 af[6];
    {
        int rb = wv << 4;
#pragma unroll
        for (int s = 0; s < 6; ++s)
            af[s] = *(const bf16x8*)(As[s >> 1] + (size_t)(rb + r15) * 64 + (s & 1) * 32 + kq * 8);
    }
    for (int t = wv; t < ntile; t += nw) {
        int tn = t + nw;
        bf16x8 afn[6];
        if (tn < ntile) {
            int rbn = tn << 4;
#pragma unroll
            for (int s = 0; s < 6; ++s)
                afn[s] = *(const bf16x8*)(As[s >> 1] + (size_t)(rbn + r15) * 64 + (s & 1) * 32 + kq * 8);
        }
        f32x4 acc[NCT];
#pragma unroll
        for (int ct = 0; ct < NCT; ++ct) acc[ct] = (f32x4){0.f, 0.f, 0.f, 0.f};
#pragma unroll
        for (int s = 0; s < 6; ++s)
#pragma unroll
            for (int ct = 0; ct < NCT; ++ct)
                acc[ct] = __builtin_amdgcn_mfma_f32_16x16x32_bf16(af[s], bfr[s][ct], acc[ct], 0, 0, 0);
        int rb = t << 4;
#pragma unroll
        for (int ct = 0; ct < NCT; ++ct) {
            int col = ct * 16 + r15;
#pragma unroll
            for (int i = 0; i < 4; ++i) {
                int row = rb + kq * 4 + i;  // C/D: col=lane&15, row=(lane>>4)*4+i  [m89]
                float v = acc[ct][i] + bs[ct];
                if (RELU) v = fmaxf(v, 0.f);
                if (BF16OUT) {
                    outb[(size_t)row * 64 + col] = f2bf(v);
                } else {
                    if (col < 40) outf[(size_t)row * 40 + col] = v;
                }
            }
        }
#pragma unroll
        for (int s = 0; s < 6; ++s) af[s] = afn[s];
    }
}

extern "C" void kernel_launch(void* const* d_in, const int* in_sizes, int n_in,
                              void* d_out, int out_size, void* d_ws, size_t ws_size,
                              hipStream_t stream) {
    const float* x   = (const float*)d_in[0];
    const int*  eidx = (const int*)d_in[1];
    const float* W1  = (const float*)d_in[2];
    const float* b1  = (const float*)d_in[3];
    const float* W2  = (const float*)d_in[4];
    const float* b2  = (const float*)d_in[5];
    float* out = (float*)d_out;

    const int CIN = 50;
    int N = in_sizes[0] / CIN;  // 100000
    int E = in_sizes[1] / 2;    // 1600000
    const int* row = eidx;
    const int* col = eidx + E;

    char* w = (char*)d_ws;
    auto carve = [&](size_t b) -> char* {
        char* p = w;
        w += (b + 255) & ~(size_t)255;
        return p;
    };
    int*    deg     = (int*)carve((size_t)N * 4);
    int*    start   = (int*)carve((size_t)N * 4);
    int*    cursor  = (int*)carve((size_t)N * 4);
    int*    counter = (int*)carve(256);
    float*  dinv    = (float*)carve((size_t)N * 4);
    int2*   ecc     = (int2*)carve((size_t)E * 8);
    ushort* xb      = (ushort*)carve((size_t)N * 64 * 2);
    ushort* B1b     = (ushort*)carve((size_t)N * 64 * 2);
    ushort* B2b     = (ushort*)carve((size_t)N * 64 * 2);
    ushort* Hb      = (ushort*)carve((size_t)N * 64 * 2);
    ushort* Wt1     = (ushort*)carve((size_t)64 * 192 * 2);
    ushort* Wt2     = (ushort*)carve((size_t)64 * 192 * 2);
    (void)ws_size; (void)n_in; (void)out_size;

    hipMemsetAsync(deg, 0, (size_t)N * 4, stream);
    hipMemsetAsync(counter, 0, 4, stream);

    int gE = (E + 255) / 256;
    int gN = (N + 255) / 256;
    int gW = (N + 3) / 4;

    k_count<<<gE, 256, 0, stream>>>(row, deg, E);
    k_alloc<<<gN, 256, 0, stream>>>(deg, start, cursor, dinv, counter, N);
    // windowed counting-sort scatter: keep each pass's write region L2-resident
    const int PASSES = 4;
    for (int p = 0; p < PASSES; ++p) {
        int lo = (int)((long long)N * p / PASSES);
        int hi = (int)((long long)N * (p + 1) / PASSES);
        k_fill<<<gE, 256, 0, stream>>>(row, col, cursor, dinv, ecc, E, lo, hi);
    }
    k_pad_x<<<(N * 64 + 255) / 256, 256, 0, stream>>>(x, xb, N);
    k_wt<<<(2 * 64 * 192 + 255) / 256, 256, 0, stream>>>(W1, W2, Wt1, Wt2);

    int gG = 392;

    // layer 1
    k_lmul<<<gW, 256, 0, stream>>>(start, deg, ecc, dinv, xb, xb, B1b, N, 1.f, 0.f);
    k_lmul<<<gW, 256, 0, stream>>>(start, deg, ecc, dinv, B1b, xb, B2b, N, 2.f, -1.f);
    k_gemm_mfma<4, true, true><<<gG, 256, 0, stream>>>(xb, B1b, B2b, Wt1, b1, 50, Hb, nullptr, N);

    // layer 2
    k_lmul<<<gW, 256, 0, stream>>>(start, deg, ecc, dinv, Hb, Hb, B1b, N, 1.f, 0.f);
    k_lmul<<<gW, 256, 0, stream>>>(start, deg, ecc, dinv, B1b, Hb, B2b, N, 2.f, -1.f);
    k_gemm_mfma<3, false, false><<<gG, 256, 0, stream>>>(Hb, B1b, B2b, Wt2, b2, 40, nullptr, out, N);
}

// Round 5
// 455.598 us; speedup vs baseline: 2.4712x; 1.1402x over previous
//
#include <hip/hip_runtime.h>
#include <hip/hip_bf16.h>
#include <math.h>

typedef short bf16x8 __attribute__((ext_vector_type(8)));
typedef float f32x4 __attribute__((ext_vector_type(4)));
typedef __hip_bfloat16 bf16;

static __device__ __forceinline__ float bf2f(ushort u) {
    unsigned int x = ((unsigned int)u) << 16;
    return __builtin_bit_cast(float, x);
}
static __device__ __forceinline__ ushort f2bf(float f) {
    bf16 h = __float2bfloat16(f);
    return __builtin_bit_cast(ushort, h);
}

// ---------------- CSR build ----------------

__global__ __launch_bounds__(256) void k_count(const int* __restrict__ row,
                                               int* __restrict__ deg, int E) {
    int i = blockIdx.x * 256 + threadIdx.x;
    if (i < E) atomicAdd(&deg[row[i]], 1);
}

// start = exclusive prefix of deg (wave-aggregated atomic alloc); also dinv
__global__ __launch_bounds__(256) void k_alloc(const int* __restrict__ deg,
                                               int* __restrict__ start,
                                               int* __restrict__ cursor,
                                               float* __restrict__ dinv,
                                               int* counter, int N) {
    int i = blockIdx.x * 256 + threadIdx.x;
    int lane = threadIdx.x & 63;
    int d = (i < N) ? deg[i] : 0;
    int v = d;
#pragma unroll
    for (int off = 1; off < 64; off <<= 1) {
        int t = __shfl_up(v, off);
        if (lane >= off) v += t;
    }
    int total = __shfl(v, 63);
    int base = 0;
    if (lane == 63) base = atomicAdd(counter, total);
    base = __shfl(base, 63);
    if (i < N) {
        int s = base + v - d;
        start[i] = s;
        cursor[i] = s;
        dinv[i] = (d > 0) ? 1.0f / sqrtf((float)d) : 0.0f;
    }
}

// windowed fill: only edges whose row is in [lo,hi) are placed this pass, so the
// scattered int2 writes stay within a ~3.2MB region that fits a per-XCD L2.
__global__ __launch_bounds__(256) void k_fill(const int* __restrict__ row,
                                              const int* __restrict__ col,
                                              int* __restrict__ cursor,
                                              const float* __restrict__ dinv,
                                              int2* __restrict__ ecc, int E,
                                              int lo, int hi) {
    int i = blockIdx.x * 256 + threadIdx.x;
    if (i >= E) return;
    int r = row[i];
    if (r < lo || r >= hi) return;
    int c = col[i];
    int p = atomicAdd(&cursor[r], 1);
    int2 pk;
    pk.x = c;
    pk.y = __float_as_int(dinv[c]);
    ecc[p] = pk;
}

// ---------------- layout prep ----------------
__global__ __launch_bounds__(256) void k_pad_x(const float* __restrict__ x,
                                               ushort* __restrict__ xb, int N) {
    int t = blockIdx.x * 256 + threadIdx.x;
    if (t >= N * 64) return;
    int i = t >> 6, c = t & 63;
    float v = (c < 50) ? x[(size_t)i * 50 + c] : 0.f;
    xb[t] = f2bf(v);
}

// both weight transposes in one launch: Wt[cout][arr*64+c], bf16, zero-padded
__global__ __launch_bounds__(256) void k_wt(const float* __restrict__ W1,
                                            const float* __restrict__ W2,
                                            ushort* __restrict__ Wt1,
                                            ushort* __restrict__ Wt2) {
    int t = blockIdx.x * 256 + threadIdx.x;
    if (t >= 2 * 64 * 192) return;
    int half = t / (64 * 192), u = t % (64 * 192);
    int cout = u / 192, k = u % 192;
    int arr = k >> 6, c = k & 63;
    if (half == 0) {
        float v = (c < 50) ? W1[(size_t)(arr * 50 + c) * 50 + cout] : 0.f;
        Wt1[u] = f2bf(v);
    } else {
        float v = (c < 50 && cout < 40) ? W2[(size_t)(arr * 50 + c) * 40 + cout] : 0.f;
        Wt2[u] = f2bf(v);
    }
}

// ---------------- L_hat multiply, half-wave channel split ----------------
// out[i][c] = -a*dinv[i]*sum_e w_e * v[col_e][c] + bc*other[i][c]
// Rows are bf16[64] = 128B. Lanes 0-31 handle even-k edges, lanes 32-63 odd-k:
// each lane loads a uint (2 packed bf16 channels), so ONE gather instruction
// fetches TWO edges' full rows (2 lines). 8-slot (16-edge) pipelined main loop
// keeps up to 16 edge-lines in flight per wave.
__global__ __launch_bounds__(256) void k_lmul(const int* __restrict__ start,
                                              const int* __restrict__ deg,
                                              const int2* __restrict__ ecc,
                                              const float* __restrict__ dinv,
                                              const ushort* __restrict__ v,
                                              const ushort* __restrict__ other,
                                              ushort* __restrict__ out, int N,
                                              float a, float bc) {
    int wid = threadIdx.x >> 6, lane = threadIdx.x & 63;
    int i = blockIdx.x * 4 + wid;
    if (i >= N) return;
    int h = lane >> 5;   // half-wave id: edge parity
    int c = lane & 31;   // channel-pair index (channels 2c, 2c+1)
    int s = start[i];
    int d = deg[i];
    const char* vB = (const char*)v;
    float acc0 = 0.f, acc1 = 0.f;
    int k = 0;

    if (d >= 16) {
        int2 e[8];
#pragma unroll
        for (int j = 0; j < 8; ++j) e[j] = ecc[s + 2 * j + h];
        for (; k + 32 <= d; k += 16) {
            int2 n[8];
#pragma unroll
            for (int j = 0; j < 8; ++j) n[j] = ecc[s + k + 16 + 2 * j + h];
            uint g[8];
#pragma unroll
            for (int j = 0; j < 8; ++j)
                g[j] = *(const uint*)(vB + ((size_t)(uint)e[j].x << 7) + (c << 2));
#pragma unroll
            for (int j = 0; j < 8; ++j) {
                float w = __int_as_float(e[j].y);
                acc0 += w * bf2f((ushort)g[j]);
                acc1 += w * bf2f((ushort)(g[j] >> 16));
            }
#pragma unroll
            for (int j = 0; j < 8; ++j) e[j] = n[j];
        }
        {   // drain preloaded block: edges [k, k+16)
            uint g[8];
#pragma unroll
            for (int j = 0; j < 8; ++j)
                g[j] = *(const uint*)(vB + ((size_t)(uint)e[j].x << 7) + (c << 2));
#pragma unroll
            for (int j = 0; j < 8; ++j) {
                float w = __int_as_float(e[j].y);
                acc0 += w * bf2f((ushort)g[j]);
                acc1 += w * bf2f((ushort)(g[j] >> 16));
            }
            k += 16;
        }
    }
    if (k + 8 <= d) {  // one 4-slot block
        int2 e[4];
#pragma unroll
        for (int j = 0; j < 4; ++j) e[j] = ecc[s + k + 2 * j + h];
        uint g[4];
#pragma unroll
        for (int j = 0; j < 4; ++j)
            g[j] = *(const uint*)(vB + ((size_t)(uint)e[j].x << 7) + (c << 2));
#pragma unroll
        for (int j = 0; j < 4; ++j) {
            float w = __int_as_float(e[j].y);
            acc0 += w * bf2f((ushort)g[j]);
            acc1 += w * bf2f((ushort)(g[j] >> 16));
        }
        k += 8;
    }
    for (; k + 2 <= d; k += 2) {  // pair steps
        int2 e = ecc[s + k + h];
        uint g = *(const uint*)(vB + ((size_t)(uint)e.x << 7) + (c << 2));
        float w = __int_as_float(e.y);
        acc0 += w * bf2f((ushort)g);
        acc1 += w * bf2f((ushort)(g >> 16));
    }
    if (k < d) {  // odd tail: only half 0 contributes
        int2 e = ecc[s + k];
        uint g = *(const uint*)(vB + ((size_t)(uint)e.x << 7) + (c << 2));
        float w = h ? 0.f : __int_as_float(e.y);
        acc0 += w * bf2f((ushort)g);
        acc1 += w * bf2f((ushort)(g >> 16));
    }

    // combine the two half-wave partial sums (same channels, disjoint edges)
    acc0 += __shfl_xor(acc0, 32);
    acc1 += __shfl_xor(acc1, 32);

    float di = dinv[i];
    float r0 = -a * di * acc0;
    float r1 = -a * di * acc1;
    if (bc != 0.f) {
        uint ov = *(const uint*)((const char*)other + ((size_t)(uint)i << 7) + (c << 2));
        r0 += bc * bf2f((ushort)ov);
        r1 += bc * bf2f((ushort)(ov >> 16));
    }
    if (h == 0) {
        uint pk = (uint)f2bf(r0) | ((uint)f2bf(r1) << 16);
        *(uint*)((char*)out + ((size_t)(uint)i << 7) + (c << 2)) = pk;
    }
}

// ---------------- MFMA GEMM: C[N, NCT*16] = [A0|A1|A2] @ Wt^T + b ----------------
// depth-2 pipeline on the A fragments (next tile's loads issue before MFMAs).
template <int NCT, bool RELU, bool BF16OUT>
__global__ __launch_bounds__(256) void k_gemm_mfma(const ushort* __restrict__ A0,
                                                   const ushort* __restrict__ A1,
                                                   const ushort* __restrict__ A2,
                                                   const ushort* __restrict__ Wt,
                                                   const float* __restrict__ bias,
                                                   int biasN,
                                                   ushort* __restrict__ outb,
                                                   float* __restrict__ outf, int N) {
    int lane = threadIdx.x & 63;
    int wv = blockIdx.x * 4 + (threadIdx.x >> 6);
    int nw = gridDim.x * 4;
    int r15 = lane & 15, kq = lane >> 4;

    bf16x8 bfr[6][NCT];
#pragma unroll
    for (int s = 0; s < 6; ++s)
#pragma unroll
        for (int ct = 0; ct < NCT; ++ct)
            bfr[s][ct] = *(const bf16x8*)(Wt + (size_t)(ct * 16 + r15) * 192 + s * 32 + kq * 8);
    float bs[NCT];
#pragma unroll
    for (int ct = 0; ct < NCT; ++ct) {
        int col = ct * 16 + r15;
        bs[ct] = (col < biasN) ? bias[col] : 0.f;
    }

    const ushort* As[3] = {A0, A1, A2};
    int ntile = N >> 4;
    if (wv >= ntile) return;
    bf16x8 af[6];
    {
        int rb = wv << 4;
#pragma unroll
        for (int s = 0; s < 6; ++s)
            af[s] = *(const bf16x8*)(As[s >> 1] + (size_t)(rb + r15) * 64 + (s & 1) * 32 + kq * 8);
    }
    for (int t = wv; t < ntile; t += nw) {
        int tn = t + nw;
        bf16x8 afn[6];
        if (tn < ntile) {
            int rbn = tn << 4;
#pragma unroll
            for (int s = 0; s < 6; ++s)
                afn[s] = *(const bf16x8*)(As[s >> 1] + (size_t)(rbn + r15) * 64 + (s & 1) * 32 + kq * 8);
        }
        f32x4 acc[NCT];
#pragma unroll
        for (int ct = 0; ct < NCT; ++ct) acc[ct] = (f32x4){0.f, 0.f, 0.f, 0.f};
#pragma unroll
        for (int s = 0; s < 6; ++s)
#pragma unroll
            for (int ct = 0; ct < NCT; ++ct)
                acc[ct] = __builtin_amdgcn_mfma_f32_16x16x32_bf16(af[s], bfr[s][ct], acc[ct], 0, 0, 0);
        int rb = t << 4;
#pragma unroll
        for (int ct = 0; ct < NCT; ++ct) {
            int col = ct * 16 + r15;
#pragma unroll
            for (int i = 0; i < 4; ++i) {
                int row = rb + kq * 4 + i;  // C/D: col=lane&15, row=(lane>>4)*4+i  [m89]
                float v = acc[ct][i] + bs[ct];
                if (RELU) v = fmaxf(v, 0.f);
                if (BF16OUT) {
                    outb[(size_t)row * 64 + col] = f2bf(v);
                } else {
                    if (col < 40) outf[(size_t)row * 40 + col] = v;
                }
            }
        }
#pragma unroll
        for (int s = 0; s < 6; ++s) af[s] = afn[s];
    }
}

extern "C" void kernel_launch(void* const* d_in, const int* in_sizes, int n_in,
                              void* d_out, int out_size, void* d_ws, size_t ws_size,
                              hipStream_t stream) {
    const float* x   = (const float*)d_in[0];
    const int*  eidx = (const int*)d_in[1];
    const float* W1  = (const float*)d_in[2];
    const float* b1  = (const float*)d_in[3];
    const float* W2  = (const float*)d_in[4];
    const float* b2  = (const float*)d_in[5];
    float* out = (float*)d_out;

    const int CIN = 50;
    int N = in_sizes[0] / CIN;  // 100000
    int E = in_sizes[1] / 2;    // 1600000
    const int* row = eidx;
    const int* col = eidx + E;

    char* w = (char*)d_ws;
    auto carve = [&](size_t b) -> char* {
        char* p = w;
        w += (b + 255) & ~(size_t)255;
        return p;
    };
    int*    deg     = (int*)carve((size_t)N * 4);
    int*    start   = (int*)carve((size_t)N * 4);
    int*    cursor  = (int*)carve((size_t)N * 4);
    int*    counter = (int*)carve(256);
    float*  dinv    = (float*)carve((size_t)N * 4);
    int2*   ecc     = (int2*)carve((size_t)E * 8);
    ushort* xb      = (ushort*)carve((size_t)N * 64 * 2);
    ushort* B1b     = (ushort*)carve((size_t)N * 64 * 2);
    ushort* B2b     = (ushort*)carve((size_t)N * 64 * 2);
    ushort* Hb      = (ushort*)carve((size_t)N * 64 * 2);
    ushort* Wt1     = (ushort*)carve((size_t)64 * 192 * 2);
    ushort* Wt2     = (ushort*)carve((size_t)64 * 192 * 2);
    (void)ws_size; (void)n_in; (void)out_size;

    hipMemsetAsync(deg, 0, (size_t)N * 4, stream);
    hipMemsetAsync(counter, 0, 4, stream);

    int gE = (E + 255) / 256;
    int gN = (N + 255) / 256;
    int gW = (N + 3) / 4;

    k_count<<<gE, 256, 0, stream>>>(row, deg, E);
    k_alloc<<<gN, 256, 0, stream>>>(deg, start, cursor, dinv, counter, N);
    const int PASSES = 4;
    for (int p = 0; p < PASSES; ++p) {
        int lo = (int)((long long)N * p / PASSES);
        int hi = (int)((long long)N * (p + 1) / PASSES);
        k_fill<<<gE, 256, 0, stream>>>(row, col, cursor, dinv, ecc, E, lo, hi);
    }
    k_pad_x<<<(N * 64 + 255) / 256, 256, 0, stream>>>(x, xb, N);
    k_wt<<<(2 * 64 * 192 + 255) / 256, 256, 0, stream>>>(W1, W2, Wt1, Wt2);

    int gG = 392;

    // layer 1
    k_lmul<<<gW, 256, 0, stream>>>(start, deg, ecc, dinv, xb, xb, B1b, N, 1.f, 0.f);
    k_lmul<<<gW, 256, 0, stream>>>(start, deg, ecc, dinv, B1b, xb, B2b, N, 2.f, -1.f);
    k_gemm_mfma<4, true, true><<<gG, 256, 0, stream>>>(xb, B1b, B2b, Wt1, b1, 50, Hb, nullptr, N);

    // layer 2
    k_lmul<<<gW, 256, 0, stream>>>(start, deg, ecc, dinv, Hb, Hb, B1b, N, 1.f, 0.f);
    k_lmul<<<gW, 256, 0, stream>>>(start, deg, ecc, dinv, B1b, Hb, B2b, N, 2.f, -1.f);
    k_gemm_mfma<3, false, false><<<gG, 256, 0, stream>>>(Hb, B1b, B2b, Wt2, b2, 40, nullptr, out, N);
}

// Round 6
// 416.600 us; speedup vs baseline: 2.7026x; 1.0936x over previous
//
#include <hip/hip_runtime.h>
#include <hip/hip_bf16.h>
#include <math.h>

typedef short bf16x8 __attribute__((ext_vector_type(8)));
typedef float f32x4 __attribute__((ext_vector_type(4)));
typedef __hip_bfloat16 bf16;

#define NW 4    // row windows
#define BSL 64  // edge slices per window

static __device__ __forceinline__ float bf2f(ushort u) {
    unsigned int x = ((unsigned int)u) << 16;
    return __builtin_bit_cast(float, x);
}
static __device__ __forceinline__ ushort f2bf(float f) {
    bf16 h = __float2bfloat16(f);
    return __builtin_bit_cast(ushort, h);
}

// ---------------- CSR build: windowed counting sort, no global atomics ----------------

// per-(window,slice) LDS histogram; 2 rows packed per uint (ushort counts)
__global__ __launch_bounds__(256) void k_hist(const int* __restrict__ row,
                                              uint* __restrict__ histU,
                                              int E, int N, int W) {
    __shared__ uint h[12544];
    int blk = blockIdx.x, w = blk / BSL, b = blk % BSL;
    int w0 = w * W, WH = W >> 1;
    int wlen = min(W, N - w0);
    for (int t = threadIdx.x; t < WH; t += 256) h[t] = 0;
    __syncthreads();
    int e0 = (int)((long long)E * b / BSL);
    int e1 = (int)((long long)E * (b + 1) / BSL);
    for (int i = e0 + threadIdx.x; i < e1; i += 256) {
        int r = row[i] - w0;
        if ((unsigned)r < (unsigned)wlen)
            atomicAdd(&h[r >> 1], 1u << ((r & 1) << 4));
    }
    __syncthreads();
    uint* dst = histU + (size_t)(w * BSL + b) * WH;
    for (int t = threadIdx.x; t < WH; t += 256) dst[t] = h[t];
}

// per row-pair: turn per-slice counts into per-slice exclusive offsets (in place),
// emit deg + dinv
__global__ __launch_bounds__(256) void k_rowsum(uint* __restrict__ histU,
                                                int* __restrict__ deg,
                                                float* __restrict__ dinv,
                                                int N, int W) {
    int q = blockIdx.x * 256 + threadIdx.x;
    int NH = (N + 1) >> 1;
    if (q >= NH) return;
    int r0 = 2 * q;
    int w = r0 / W, WH = W >> 1;
    int qw = (r0 - w * W) >> 1;
    uint run0 = 0, run1 = 0;
    uint* p = histU + (size_t)(w * BSL) * WH + qw;
#pragma unroll 8
    for (int b = 0; b < BSL; ++b) {
        uint v = p[(size_t)b * WH];
        p[(size_t)b * WH] = run0 | (run1 << 16);
        run0 += v & 0xffffu;
        run1 += v >> 16;
    }
    int d0 = (int)run0, d1 = (int)run1;
    deg[r0] = d0;
    dinv[r0] = d0 > 0 ? 1.0f / sqrtf((float)d0) : 0.0f;
    if (r0 + 1 < N) {
        deg[r0 + 1] = d1;
        dinv[r0 + 1] = d1 > 0 ? 1.0f / sqrtf((float)d1) : 0.0f;
    }
}

// start = exclusive prefix of deg (wave-aggregated atomic alloc)
__global__ __launch_bounds__(256) void k_alloc(const int* __restrict__ deg,
                                               int* __restrict__ start,
                                               int* counter, int N) {
    int i = blockIdx.x * 256 + threadIdx.x;
    int lane = threadIdx.x & 63;
    int d = (i < N) ? deg[i] : 0;
    int v = d;
#pragma unroll
    for (int off = 1; off < 64; off <<= 1) {
        int t = __shfl_up(v, off);
        if (lane >= off) v += t;
    }
    int total = __shfl(v, 63);
    int base = 0;
    if (lane == 63) base = atomicAdd(counter, total);
    base = __shfl(base, 63);
    if (i < N) start[i] = base + v - d;
}

// deterministic fill: slot = start[r] + slice-offset + LDS cursor
__global__ __launch_bounds__(256) void k_fill2(const int* __restrict__ row,
                                               const int* __restrict__ col,
                                               const int* __restrict__ start,
                                               const uint* __restrict__ histU,
                                               const float* __restrict__ dinv,
                                               int2* __restrict__ ecc,
                                               int E, int N, int W) {
    __shared__ int cur[25088];
    int blk = blockIdx.x, w = blk / BSL, b = blk % BSL;
    int w0 = w * W, WH = W >> 1;
    int wlen = min(W, N - w0);
    const uint* hb = histU + (size_t)(w * BSL + b) * WH;
    for (int j = threadIdx.x; 2 * j < wlen; j += 256) {
        uint off = hb[j];
        int r0 = w0 + 2 * j;
        cur[2 * j] = start[r0] + (int)(off & 0xffffu);
        if (2 * j + 1 < wlen) cur[2 * j + 1] = start[r0 + 1] + (int)(off >> 16);
    }
    __syncthreads();
    int e0 = (int)((long long)E * b / BSL);
    int e1 = (int)((long long)E * (b + 1) / BSL);
    for (int i = e0 + threadIdx.x; i < e1; i += 256) {
        int r = row[i] - w0;
        if ((unsigned)r < (unsigned)wlen) {
            int c = col[i];
            int p = atomicAdd(&cur[r], 1);
            int2 pk;
            pk.x = c;
            pk.y = __float_as_int(dinv[c]);
            ecc[p] = pk;
        }
    }
}

// ---------------- layout prep ----------------
__global__ __launch_bounds__(256) void k_pad_x(const float* __restrict__ x,
                                               ushort* __restrict__ xb, int N) {
    int t = blockIdx.x * 256 + threadIdx.x;
    if (t >= N * 64) return;
    int i = t >> 6, c = t & 63;
    float v = (c < 50) ? x[(size_t)i * 50 + c] : 0.f;
    xb[t] = f2bf(v);
}

__global__ __launch_bounds__(256) void k_wt(const float* __restrict__ W1,
                                            const float* __restrict__ W2,
                                            ushort* __restrict__ Wt1,
                                            ushort* __restrict__ Wt2) {
    int t = blockIdx.x * 256 + threadIdx.x;
    if (t >= 2 * 64 * 192) return;
    int half = t / (64 * 192), u = t % (64 * 192);
    int cout = u / 192, k = u % 192;
    int arr = k >> 6, c = k & 63;
    if (half == 0) {
        float v = (c < 50) ? W1[(size_t)(arr * 50 + c) * 50 + cout] : 0.f;
        Wt1[u] = f2bf(v);
    } else {
        float v = (c < 50 && cout < 40) ? W2[(size_t)(arr * 50 + c) * 40 + cout] : 0.f;
        Wt2[u] = f2bf(v);
    }
}

// ---------------- L_hat multiply, half-wave channel split ----------------
__global__ __launch_bounds__(256) void k_lmul(const int* __restrict__ start,
                                              const int* __restrict__ deg,
                                              const int2* __restrict__ ecc,
                                              const float* __restrict__ dinv,
                                              const ushort* __restrict__ v,
                                              const ushort* __restrict__ other,
                                              ushort* __restrict__ out, int N,
                                              float a, float bc) {
    int wid = threadIdx.x >> 6, lane = threadIdx.x & 63;
    int i = blockIdx.x * 4 + wid;
    if (i >= N) return;
    int h = lane >> 5;
    int c = lane & 31;
    int s = start[i];
    int d = deg[i];
    const char* vB = (const char*)v;
    float acc0 = 0.f, acc1 = 0.f;
    int k = 0;

    if (d >= 16) {
        int2 e[8];
#pragma unroll
        for (int j = 0; j < 8; ++j) e[j] = ecc[s + 2 * j + h];
        for (; k + 32 <= d; k += 16) {
            int2 n[8];
#pragma unroll
            for (int j = 0; j < 8; ++j) n[j] = ecc[s + k + 16 + 2 * j + h];
            uint g[8];
#pragma unroll
            for (int j = 0; j < 8; ++j)
                g[j] = *(const uint*)(vB + ((size_t)(uint)e[j].x << 7) + (c << 2));
#pragma unroll
            for (int j = 0; j < 8; ++j) {
                float w = __int_as_float(e[j].y);
                acc0 += w * bf2f((ushort)g[j]);
                acc1 += w * bf2f((ushort)(g[j] >> 16));
            }
#pragma unroll
            for (int j = 0; j < 8; ++j) e[j] = n[j];
        }
        {
            uint g[8];
#pragma unroll
            for (int j = 0; j < 8; ++j)
                g[j] = *(const uint*)(vB + ((size_t)(uint)e[j].x << 7) + (c << 2));
#pragma unroll
            for (int j = 0; j < 8; ++j) {
                float w = __int_as_float(e[j].y);
                acc0 += w * bf2f((ushort)g[j]);
                acc1 += w * bf2f((ushort)(g[j] >> 16));
            }
            k += 16;
        }
    }
    if (k + 8 <= d) {
        int2 e[4];
#pragma unroll
        for (int j = 0; j < 4; ++j) e[j] = ecc[s + k + 2 * j + h];
        uint g[4];
#pragma unroll
        for (int j = 0; j < 4; ++j)
            g[j] = *(const uint*)(vB + ((size_t)(uint)e[j].x << 7) + (c << 2));
#pragma unroll
        for (int j = 0; j < 4; ++j) {
            float w = __int_as_float(e[j].y);
            acc0 += w * bf2f((ushort)g[j]);
            acc1 += w * bf2f((ushort)(g[j] >> 16));
        }
        k += 8;
    }
    for (; k + 2 <= d; k += 2) {
        int2 e = ecc[s + k + h];
        uint g = *(const uint*)(vB + ((size_t)(uint)e.x << 7) + (c << 2));
        float w = __int_as_float(e.y);
        acc0 += w * bf2f((ushort)g);
        acc1 += w * bf2f((ushort)(g >> 16));
    }
    if (k < d) {
        int2 e = ecc[s + k];
        uint g = *(const uint*)(vB + ((size_t)(uint)e.x << 7) + (c << 2));
        float w = h ? 0.f : __int_as_float(e.y);
        acc0 += w * bf2f((ushort)g);
        acc1 += w * bf2f((ushort)(g >> 16));
    }

    acc0 += __shfl_xor(acc0, 32);
    acc1 += __shfl_xor(acc1, 32);

    float di = dinv[i];
    float r0 = -a * di * acc0;
    float r1 = -a * di * acc1;
    if (bc != 0.f) {
        uint ov = *(const uint*)((const char*)other + ((size_t)(uint)i << 7) + (c << 2));
        r0 += bc * bf2f((ushort)ov);
        r1 += bc * bf2f((ushort)(ov >> 16));
    }
    if (h == 0) {
        uint pk = (uint)f2bf(r0) | ((uint)f2bf(r1) << 16);
        *(uint*)((char*)out + ((size_t)(uint)i << 7) + (c << 2)) = pk;
    }
}

// ---------------- MFMA GEMM: C[N, NCT*16] = [A0|A1|A2] @ Wt^T + b ----------------
template <int NCT, bool RELU, bool BF16OUT>
__global__ __launch_bounds__(256) void k_gemm_mfma(const ushort* __restrict__ A0,
                                                   const ushort* __restrict__ A1,
                                                   const ushort* __restrict__ A2,
                                                   const ushort* __restrict__ Wt,
                                                   const float* __restrict__ bias,
                                                   int biasN,
                                                   ushort* __restrict__ outb,
                                                   float* __restrict__ outf, int N) {
    int lane = threadIdx.x & 63;
    int wv = blockIdx.x * 4 + (threadIdx.x >> 6);
    int nw = gridDim.x * 4;
    int r15 = lane & 15, kq = lane >> 4;

    bf16x8 bfr[6][NCT];
#pragma unroll
    for (int s = 0; s < 6; ++s)
#pragma unroll
        for (int ct = 0; ct < NCT; ++ct)
            bfr[s][ct] = *(const bf16x8*)(Wt + (size_t)(ct * 16 + r15) * 192 + s * 32 + kq * 8);
    float bs[NCT];
#pragma unroll
    for (int ct = 0; ct < NCT; ++ct) {
        int col = ct * 16 + r15;
        bs[ct] = (col < biasN) ? bias[col] : 0.f;
    }

    const ushort* As[3] = {A0, A1, A2};
    int ntile = N >> 4;
    if (wv >= ntile) return;
    bf16x8 af[6];
    {
        int rb = wv << 4;
#pragma unroll
        for (int s = 0; s < 6; ++s)
            af[s] = *(const bf16x8*)(As[s >> 1] + (size_t)(rb + r15) * 64 + (s & 1) * 32 + kq * 8);
    }
    for (int t = wv; t < ntile; t += nw) {
        int tn = t + nw;
        bf16x8 afn[6];
        if (tn < ntile) {
            int rbn = tn << 4;
#pragma unroll
            for (int s = 0; s < 6; ++s)
                afn[s] = *(const bf16x8*)(As[s >> 1] + (size_t)(rbn + r15) * 64 + (s & 1) * 32 + kq * 8);
        }
        f32x4 acc[NCT];
#pragma unroll
        for (int ct = 0; ct < NCT; ++ct) acc[ct] = (f32x4){0.f, 0.f, 0.f, 0.f};
#pragma unroll
        for (int s = 0; s < 6; ++s)
#pragma unroll
            for (int ct = 0; ct < NCT; ++ct)
                acc[ct] = __builtin_amdgcn_mfma_f32_16x16x32_bf16(af[s], bfr[s][ct], acc[ct], 0, 0, 0);
        int rb = t << 4;
#pragma unroll
        for (int ct = 0; ct < NCT; ++ct) {
            int col = ct * 16 + r15;
#pragma unroll
            for (int i = 0; i < 4; ++i) {
                int row = rb + kq * 4 + i;  // C/D: col=lane&15, row=(lane>>4)*4+i  [m89]
                float v = acc[ct][i] + bs[ct];
                if (RELU) v = fmaxf(v, 0.f);
                if (BF16OUT) {
                    outb[(size_t)row * 64 + col] = f2bf(v);
                } else {
                    if (col < 40) outf[(size_t)row * 40 + col] = v;
                }
            }
        }
#pragma unroll
        for (int s = 0; s < 6; ++s) af[s] = afn[s];
    }
}

extern "C" void kernel_launch(void* const* d_in, const int* in_sizes, int n_in,
                              void* d_out, int out_size, void* d_ws, size_t ws_size,
                              hipStream_t stream) {
    const float* x   = (const float*)d_in[0];
    const int*  eidx = (const int*)d_in[1];
    const float* W1  = (const float*)d_in[2];
    const float* b1  = (const float*)d_in[3];
    const float* W2  = (const float*)d_in[4];
    const float* b2  = (const float*)d_in[5];
    float* out = (float*)d_out;

    const int CIN = 50;
    int N = in_sizes[0] / CIN;  // 100000
    int E = in_sizes[1] / 2;    // 1600000
    const int* row = eidx;
    const int* col = eidx + E;

    int W = ((N + NW - 1) / NW + 1) & ~1;  // even window size (25000)
    int WH = W >> 1;

    char* wsp = (char*)d_ws;
    auto carve = [&](size_t b) -> char* {
        char* p = wsp;
        wsp += (b + 255) & ~(size_t)255;
        return p;
    };
    int*    deg     = (int*)carve((size_t)N * 4);
    int*    startA  = (int*)carve((size_t)N * 4);
    int*    counter = (int*)carve(256);
    float*  dinv    = (float*)carve((size_t)N * 4);
    int2*   ecc     = (int2*)carve((size_t)E * 8);
    ushort* xb      = (ushort*)carve((size_t)N * 64 * 2);
    ushort* B1b     = (ushort*)carve((size_t)N * 64 * 2);
    ushort* B2b     = (ushort*)carve((size_t)N * 64 * 2);  // also aliased as histU
    ushort* Hb      = (ushort*)carve((size_t)N * 64 * 2);
    ushort* Wt1     = (ushort*)carve((size_t)64 * 192 * 2);
    ushort* Wt2     = (ushort*)carve((size_t)64 * 192 * 2);
    uint*   histU   = (uint*)B2b;  // NW*BSL*WH*4 = 12.8MB <= N*128B; consumed before lmul-2
    (void)ws_size; (void)n_in; (void)out_size;

    hipMemsetAsync(counter, 0, 4, stream);

    int gN = (N + 255) / 256;
    int gW = (N + 3) / 4;

    k_hist<<<NW * BSL, 256, 0, stream>>>(row, histU, E, N, W);
    k_rowsum<<<((N + 1) / 2 + 255) / 256, 256, 0, stream>>>(histU, deg, dinv, N, W);
    k_alloc<<<gN, 256, 0, stream>>>(deg, startA, counter, N);
    k_fill2<<<NW * BSL, 256, 0, stream>>>(row, col, startA, histU, dinv, ecc, E, N, W);
    k_pad_x<<<(N * 64 + 255) / 256, 256, 0, stream>>>(x, xb, N);
    k_wt<<<(2 * 64 * 192 + 255) / 256, 256, 0, stream>>>(W1, W2, Wt1, Wt2);

    int gG = 392;

    // layer 1
    k_lmul<<<gW, 256, 0, stream>>>(startA, deg, ecc, dinv, xb, xb, B1b, N, 1.f, 0.f);
    k_lmul<<<gW, 256, 0, stream>>>(startA, deg, ecc, dinv, B1b, xb, B2b, N, 2.f, -1.f);
    k_gemm_mfma<4, true, true><<<gG, 256, 0, stream>>>(xb, B1b, B2b, Wt1, b1, 50, Hb, nullptr, N);

    // layer 2
    k_lmul<<<gW, 256, 0, stream>>>(startA, deg, ecc, dinv, Hb, Hb, B1b, N, 1.f, 0.f);
    k_lmul<<<gW, 256, 0, stream>>>(startA, deg, ecc, dinv, B1b, Hb, B2b, N, 2.f, -1.f);
    k_gemm_mfma<3, false, false><<<gG, 256, 0, stream>>>(Hb, B1b, B2b, Wt2, b2, 40, nullptr, out, N);
}

// Round 7
// 365.518 us; speedup vs baseline: 3.0803x; 1.1398x over previous
//
#include <hip/hip_runtime.h>
#include <hip/hip_bf16.h>
#include <math.h>

typedef short bf16x8 __attribute__((ext_vector_type(8)));
typedef float f32x4 __attribute__((ext_vector_type(4)));
typedef __hip_bfloat16 bf16;

#define NW 8    // row windows (= XCDs; window w runs on xcd w via bid&7)
#define BSL 32  // edge slices per window (= CUs per XCD)

static __device__ __forceinline__ float bf2f(ushort u) {
    unsigned int x = ((unsigned int)u) << 16;
    return __builtin_bit_cast(float, x);
}
static __device__ __forceinline__ ushort f2bf(float f) {
    bf16 h = __float2bfloat16(f);
    return __builtin_bit_cast(ushort, h);
}

// ---------------- CSR build: windowed counting sort, no global atomics ----------------
// block -> (window, slice): xcd = bid&7 = window, slice = bid>>3. All writers of a
// window's ecc segment live on ONE XCD, so its L2 absorbs the 8B scatter writes.

// per-(window,slice) LDS histogram; 2 rows packed per uint (ushort counts)
__global__ __launch_bounds__(1024) void k_hist(const int* __restrict__ row,
                                               uint* __restrict__ histU,
                                               int E, int N, int W) {
    __shared__ uint h[6400];
    int bid = blockIdx.x, w = bid & 7, b = bid >> 3;
    int w0 = w * W, WH = W >> 1;
    int wlen = min(W, N - w0);
    for (int t = threadIdx.x; t < WH; t += 1024) h[t] = 0;
    __syncthreads();
    int e0 = (int)((long long)E * b / BSL);
    int e1 = (int)((long long)E * (b + 1) / BSL);
    for (int i = e0 + threadIdx.x; i < e1; i += 1024) {
        int r = row[i] - w0;
        if ((unsigned)r < (unsigned)wlen)
            atomicAdd(&h[r >> 1], 1u << ((r & 1) << 4));
    }
    __syncthreads();
    uint* dst = histU + (size_t)(w * BSL + b) * WH;
    for (int t = threadIdx.x; t < WH; t += 1024) dst[t] = h[t];
}

// per row-pair: per-slice counts -> per-slice exclusive offsets (in place); deg+dinv
__global__ __launch_bounds__(256) void k_rowsum(uint* __restrict__ histU,
                                                int* __restrict__ deg,
                                                float* __restrict__ dinv,
                                                int N, int W) {
    int q = blockIdx.x * 256 + threadIdx.x;
    int NH = (N + 1) >> 1;
    if (q >= NH) return;
    int r0 = 2 * q;
    int w = r0 / W, WH = W >> 1;
    int qw = (r0 - w * W) >> 1;
    uint run0 = 0, run1 = 0;
    uint* p = histU + (size_t)(w * BSL) * WH + qw;
#pragma unroll 8
    for (int b = 0; b < BSL; ++b) {
        uint v = p[(size_t)b * WH];
        p[(size_t)b * WH] = run0 | (run1 << 16);
        run0 += v & 0xffffu;
        run1 += v >> 16;
    }
    int d0 = (int)run0, d1 = (int)run1;
    deg[r0] = d0;
    dinv[r0] = d0 > 0 ? 1.0f / sqrtf((float)d0) : 0.0f;
    if (r0 + 1 < N) {
        deg[r0 + 1] = d1;
        dinv[r0 + 1] = d1 > 0 ? 1.0f / sqrtf((float)d1) : 0.0f;
    }
}

// start = exclusive prefix of deg (wave-aggregated atomic alloc)
__global__ __launch_bounds__(256) void k_alloc(const int* __restrict__ deg,
                                               int* __restrict__ start,
                                               int* counter, int N) {
    int i = blockIdx.x * 256 + threadIdx.x;
    int lane = threadIdx.x & 63;
    int d = (i < N) ? deg[i] : 0;
    int v = d;
#pragma unroll
    for (int off = 1; off < 64; off <<= 1) {
        int t = __shfl_up(v, off);
        if (lane >= off) v += t;
    }
    int total = __shfl(v, 63);
    int base = 0;
    if (lane == 63) base = atomicAdd(counter, total);
    base = __shfl(base, 63);
    if (i < N) start[i] = base + v - d;
}

// deterministic fill: slot = start[r] + slice-offset + LDS cursor
__global__ __launch_bounds__(1024) void k_fill2(const int* __restrict__ row,
                                                const int* __restrict__ col,
                                                const int* __restrict__ start,
                                                const uint* __restrict__ histU,
                                                const float* __restrict__ dinv,
                                                int2* __restrict__ ecc,
                                                int E, int N, int W) {
    __shared__ int cur[12800];
    int bid = blockIdx.x, w = bid & 7, b = bid >> 3;
    int w0 = w * W, WH = W >> 1;
    int wlen = min(W, N - w0);
    const uint* hb = histU + (size_t)(w * BSL + b) * WH;
    for (int j = threadIdx.x; 2 * j < wlen; j += 1024) {
        uint off = hb[j];
        int r0 = w0 + 2 * j;
        cur[2 * j] = start[r0] + (int)(off & 0xffffu);
        if (2 * j + 1 < wlen) cur[2 * j + 1] = start[r0 + 1] + (int)(off >> 16);
    }
    __syncthreads();
    int e0 = (int)((long long)E * b / BSL);
    int e1 = (int)((long long)E * (b + 1) / BSL);
    for (int i = e0 + threadIdx.x; i < e1; i += 1024) {
        int r = row[i] - w0;
        if ((unsigned)r < (unsigned)wlen) {
            int c = col[i];
            int p = atomicAdd(&cur[r], 1);
            int2 pk;
            pk.x = c;
            pk.y = __float_as_int(dinv[c]);
            ecc[p] = pk;
        }
    }
}

// ---------------- layout prep ----------------
__global__ __launch_bounds__(256) void k_pad_x(const float* __restrict__ x,
                                               ushort* __restrict__ xb, int N) {
    int t = blockIdx.x * 256 + threadIdx.x;
    if (t >= N * 64) return;
    int i = t >> 6, c = t & 63;
    float v = (c < 50) ? x[(size_t)i * 50 + c] : 0.f;
    xb[t] = f2bf(v);
}

__global__ __launch_bounds__(256) void k_wt(const float* __restrict__ W1,
                                            const float* __restrict__ W2,
                                            ushort* __restrict__ Wt1,
                                            ushort* __restrict__ Wt2) {
    int t = blockIdx.x * 256 + threadIdx.x;
    if (t >= 2 * 64 * 192) return;
    int half = t / (64 * 192), u = t % (64 * 192);
    int cout = u / 192, k = u % 192;
    int arr = k >> 6, c = k & 63;
    if (half == 0) {
        float v = (c < 50) ? W1[(size_t)(arr * 50 + c) * 50 + cout] : 0.f;
        Wt1[u] = f2bf(v);
    } else {
        float v = (c < 50 && cout < 40) ? W2[(size_t)(arr * 50 + c) * 40 + cout] : 0.f;
        Wt2[u] = f2bf(v);
    }
}

// ---------------- L_hat multiply, half-wave channel split ----------------
__global__ __launch_bounds__(256) void k_lmul(const int* __restrict__ start,
                                              const int* __restrict__ deg,
                                              const int2* __restrict__ ecc,
                                              const float* __restrict__ dinv,
                                              const ushort* __restrict__ v,
                                              const ushort* __restrict__ other,
                                              ushort* __restrict__ out, int N,
                                              float a, float bc) {
    int wid = threadIdx.x >> 6, lane = threadIdx.x & 63;
    int i = blockIdx.x * 4 + wid;
    if (i >= N) return;
    int h = lane >> 5;
    int c = lane & 31;
    int s = start[i];
    int d = deg[i];
    const char* vB = (const char*)v;
    float acc0 = 0.f, acc1 = 0.f;
    int k = 0;

    if (d >= 16) {
        int2 e[8];
#pragma unroll
        for (int j = 0; j < 8; ++j) e[j] = ecc[s + 2 * j + h];
        for (; k + 32 <= d; k += 16) {
            int2 n[8];
#pragma unroll
            for (int j = 0; j < 8; ++j) n[j] = ecc[s + k + 16 + 2 * j + h];
            uint g[8];
#pragma unroll
            for (int j = 0; j < 8; ++j)
                g[j] = *(const uint*)(vB + ((size_t)(uint)e[j].x << 7) + (c << 2));
#pragma unroll
            for (int j = 0; j < 8; ++j) {
                float w = __int_as_float(e[j].y);
                acc0 += w * bf2f((ushort)g[j]);
                acc1 += w * bf2f((ushort)(g[j] >> 16));
            }
#pragma unroll
            for (int j = 0; j < 8; ++j) e[j] = n[j];
        }
        {
            uint g[8];
#pragma unroll
            for (int j = 0; j < 8; ++j)
                g[j] = *(const uint*)(vB + ((size_t)(uint)e[j].x << 7) + (c << 2));
#pragma unroll
            for (int j = 0; j < 8; ++j) {
                float w = __int_as_float(e[j].y);
                acc0 += w * bf2f((ushort)g[j]);
                acc1 += w * bf2f((ushort)(g[j] >> 16));
            }
            k += 16;
        }
    }
    if (k + 8 <= d) {
        int2 e[4];
#pragma unroll
        for (int j = 0; j < 4; ++j) e[j] = ecc[s + k + 2 * j + h];
        uint g[4];
#pragma unroll
        for (int j = 0; j < 4; ++j)
            g[j] = *(const uint*)(vB + ((size_t)(uint)e[j].x << 7) + (c << 2));
#pragma unroll
        for (int j = 0; j < 4; ++j) {
            float w = __int_as_float(e[j].y);
            acc0 += w * bf2f((ushort)g[j]);
            acc1 += w * bf2f((ushort)(g[j] >> 16));
        }
        k += 8;
    }
    for (; k + 2 <= d; k += 2) {
        int2 e = ecc[s + k + h];
        uint g = *(const uint*)(vB + ((size_t)(uint)e.x << 7) + (c << 2));
        float w = __int_as_float(e.y);
        acc0 += w * bf2f((ushort)g);
        acc1 += w * bf2f((ushort)(g >> 16));
    }
    if (k < d) {
        int2 e = ecc[s + k];
        uint g = *(const uint*)(vB + ((size_t)(uint)e.x << 7) + (c << 2));
        float w = h ? 0.f : __int_as_float(e.y);
        acc0 += w * bf2f((ushort)g);
        acc1 += w * bf2f((ushort)(g >> 16));
    }

    acc0 += __shfl_xor(acc0, 32);
    acc1 += __shfl_xor(acc1, 32);

    float di = dinv[i];
    float r0 = -a * di * acc0;
    float r1 = -a * di * acc1;
    if (bc != 0.f) {
        uint ov = *(const uint*)((const char*)other + ((size_t)(uint)i << 7) + (c << 2));
        r0 += bc * bf2f((ushort)ov);
        r1 += bc * bf2f((ushort)(ov >> 16));
    }
    if (h == 0) {
        uint pk = (uint)f2bf(r0) | ((uint)f2bf(r1) << 16);
        *(uint*)((char*)out + ((size_t)(uint)i << 7) + (c << 2)) = pk;
    }
}

// ---------------- MFMA GEMM: C[N, NCT*16] = [A0|A1|A2] @ Wt^T + b ----------------
template <int NCT, bool RELU, bool BF16OUT>
__global__ __launch_bounds__(256) void k_gemm_mfma(const ushort* __restrict__ A0,
                                                   const ushort* __restrict__ A1,
                                                   const ushort* __restrict__ A2,
                                                   const ushort* __restrict__ Wt,
                                                   const float* __restrict__ bias,
                                                   int biasN,
                                                   ushort* __restrict__ outb,
                                                   float* __restrict__ outf, int N) {
    int lane = threadIdx.x & 63;
    int wv = blockIdx.x * 4 + (threadIdx.x >> 6);
    int nw = gridDim.x * 4;
    int r15 = lane & 15, kq = lane >> 4;

    bf16x8 bfr[6][NCT];
#pragma unroll
    for (int s = 0; s < 6; ++s)
#pragma unroll
        for (int ct = 0; ct < NCT; ++ct)
            bfr[s][ct] = *(const bf16x8*)(Wt + (size_t)(ct * 16 + r15) * 192 + s * 32 + kq * 8);
    float bs[NCT];
#pragma unroll
    for (int ct = 0; ct < NCT; ++ct) {
        int col = ct * 16 + r15;
        bs[ct] = (col < biasN) ? bias[col] : 0.f;
    }

    const ushort* As[3] = {A0, A1, A2};
    int ntile = N >> 4;
    if (wv >= ntile) return;
    bf16x8 af[6];
    {
        int rb = wv << 4;
#pragma unroll
        for (int s = 0; s < 6; ++s)
            af[s] = *(const bf16x8*)(As[s >> 1] + (size_t)(rb + r15) * 64 + (s & 1) * 32 + kq * 8);
    }
    for (int t = wv; t < ntile; t += nw) {
        int tn = t + nw;
        bf16x8 afn[6];
        if (tn < ntile) {
            int rbn = tn << 4;
#pragma unroll
            for (int s = 0; s < 6; ++s)
                afn[s] = *(const bf16x8*)(As[s >> 1] + (size_t)(rbn + r15) * 64 + (s & 1) * 32 + kq * 8);
        }
        f32x4 acc[NCT];
#pragma unroll
        for (int ct = 0; ct < NCT; ++ct) acc[ct] = (f32x4){0.f, 0.f, 0.f, 0.f};
#pragma unroll
        for (int s = 0; s < 6; ++s)
#pragma unroll
            for (int ct = 0; ct < NCT; ++ct)
                acc[ct] = __builtin_amdgcn_mfma_f32_16x16x32_bf16(af[s], bfr[s][ct], acc[ct], 0, 0, 0);
        int rb = t << 4;
#pragma unroll
        for (int ct = 0; ct < NCT; ++ct) {
            int col = ct * 16 + r15;
#pragma unroll
            for (int i = 0; i < 4; ++i) {
                int row = rb + kq * 4 + i;  // C/D: col=lane&15, row=(lane>>4)*4+i  [m89]
                float v = acc[ct][i] + bs[ct];
                if (RELU) v = fmaxf(v, 0.f);
                if (BF16OUT) {
                    outb[(size_t)row * 64 + col] = f2bf(v);
                } else {
                    if (col < 40) outf[(size_t)row * 40 + col] = v;
                }
            }
        }
#pragma unroll
        for (int s = 0; s < 6; ++s) af[s] = afn[s];
    }
}

extern "C" void kernel_launch(void* const* d_in, const int* in_sizes, int n_in,
                              void* d_out, int out_size, void* d_ws, size_t ws_size,
                              hipStream_t stream) {
    const float* x   = (const float*)d_in[0];
    const int*  eidx = (const int*)d_in[1];
    const float* W1  = (const float*)d_in[2];
    const float* b1  = (const float*)d_in[3];
    const float* W2  = (const float*)d_in[4];
    const float* b2  = (const float*)d_in[5];
    float* out = (float*)d_out;

    const int CIN = 50;
    int N = in_sizes[0] / CIN;  // 100000
    int E = in_sizes[1] / 2;    // 1600000
    const int* row = eidx;
    const int* col = eidx + E;

    int W = ((N + NW - 1) / NW + 1) & ~1;  // even window size (12500); must be <= 12800
    int WH = W >> 1;
    (void)WH;

    char* wsp = (char*)d_ws;
    auto carve = [&](size_t b) -> char* {
        char* p = wsp;
        wsp += (b + 255) & ~(size_t)255;
        return p;
    };
    int*    deg     = (int*)carve((size_t)N * 4);
    int*    startA  = (int*)carve((size_t)N * 4);
    int*    counter = (int*)carve(256);
    float*  dinv    = (float*)carve((size_t)N * 4);
    int2*   ecc     = (int2*)carve((size_t)E * 8);
    ushort* xb      = (ushort*)carve((size_t)N * 64 * 2);
    ushort* B1b     = (ushort*)carve((size_t)N * 64 * 2);
    ushort* B2b     = (ushort*)carve((size_t)N * 64 * 2);  // also aliased as histU
    ushort* Hb      = (ushort*)carve((size_t)N * 64 * 2);
    ushort* Wt1     = (ushort*)carve((size_t)64 * 192 * 2);
    ushort* Wt2     = (ushort*)carve((size_t)64 * 192 * 2);
    uint*   histU   = (uint*)B2b;  // NW*BSL*WH*4 = 6.4MB <= N*128B; consumed before lmul-2
    (void)ws_size; (void)n_in; (void)out_size;

    hipMemsetAsync(counter, 0, 4, stream);

    int gN = (N + 255) / 256;
    int gW = (N + 3) / 4;

    k_hist<<<NW * BSL, 1024, 0, stream>>>(row, histU, E, N, W);
    k_rowsum<<<((N + 1) / 2 + 255) / 256, 256, 0, stream>>>(histU, deg, dinv, N, W);
    k_alloc<<<gN, 256, 0, stream>>>(deg, startA, counter, N);
    k_fill2<<<NW * BSL, 1024, 0, stream>>>(row, col, startA, histU, dinv, ecc, E, N, W);
    k_pad_x<<<(N * 64 + 255) / 256, 256, 0, stream>>>(x, xb, N);
    k_wt<<<(2 * 64 * 192 + 255) / 256, 256, 0, stream>>>(W1, W2, Wt1, Wt2);

    int gG = 392;

    // layer 1
    k_lmul<<<gW, 256, 0, stream>>>(startA, deg, ecc, dinv, xb, xb, B1b, N, 1.f, 0.f);
    k_lmul<<<gW, 256, 0, stream>>>(startA, deg, ecc, dinv, B1b, xb, B2b, N, 2.f, -1.f);
    k_gemm_mfma<4, true, true><<<gG, 256, 0, stream>>>(xb, B1b, B2b, Wt1, b1, 50, Hb, nullptr, N);

    // layer 2
    k_lmul<<<gW, 256, 0, stream>>>(startA, deg, ecc, dinv, Hb, Hb, B1b, N, 1.f, 0.f);
    k_lmul<<<gW, 256, 0, stream>>>(startA, deg, ecc, dinv, B1b, Hb, B2b, N, 2.f, -1.f);
    k_gemm_mfma<3, false, false><<<gG, 256, 0, stream>>>(Hb, B1b, B2b, Wt2, b2, 40, nullptr, out, N);
}